// Round 1
// baseline (46.911 us; speedup 1.0000x reference)
//
#include <hip/hip_runtime.h>
#include <cstddef>

// ---- problem constants (from setup_inputs: fixed for this benchmark) ----
constexpr int B_   = 64;
constexpr int N_   = 2048;
constexpr int VOC  = 21;
constexpr int EMBD = 128;
constexpr int HD   = 256;
constexpr int L_   = 900;    // T_min
constexpr int R_   = 1100;   // T_max
constexpr int BSZ  = 8;      // block_size

constexpr int NB_PRE = (L_ + BSZ - 1) / BSZ;               // 113
constexpr int MIDN   = R_ - L_ + 1;                        // 201
constexpr int NB_SUF = (N_ - (R_ + 1) + BSZ - 1) / BSZ;    // 119
constexpr int NB     = NB_PRE + MIDN + NB_SUF;             // 433

constexpr float EPS_ = 1e-8f;

// output layout: bS, bX, pm_blocks, b_init_X, bmask concatenated flat
constexpr size_t OFF_BS  = 0;
constexpr size_t OFF_BX  = (size_t)B_ * NB * HD;               // 7094272
constexpr size_t OFF_PM  = OFF_BX  + (size_t)B_ * NB * 12;     // 7426816
constexpr size_t OFF_BIX = OFF_PM  + (size_t)B_ * NB;          // 7454528
constexpr size_t OFF_BM  = OFF_BIX + (size_t)B_ * NB * 12;     // 7787072

// ---- kernel A: HT2[22][256] = [emb_table @ W_w ; W_b] ----
__global__ void ht_kernel(const float* __restrict__ emb,
                          const float* __restrict__ Ww,
                          const float* __restrict__ Wb,
                          float* __restrict__ ht) {
  const int v = blockIdx.x;
  const int h = threadIdx.x;
  if (v == VOC) { ht[(size_t)VOC * HD + h] = Wb[h]; return; }
  const float* e = emb + (size_t)v * EMBD;
  float a0 = 0.f, a1 = 0.f, a2 = 0.f, a3 = 0.f;
#pragma unroll
  for (int k = 0; k < EMBD; k += 4) {
    a0 = fmaf(e[k + 0], Ww[(size_t)(k + 0) * HD + h], a0);
    a1 = fmaf(e[k + 1], Ww[(size_t)(k + 1) * HD + h], a1);
    a2 = fmaf(e[k + 2], Ww[(size_t)(k + 2) * HD + h], a2);
    a3 = fmaf(e[k + 3], Ww[(size_t)(k + 3) * HD + h], a3);
  }
  ht[(size_t)v * HD + h] = (a0 + a1) + (a2 + a3);
}

// ---- kernel B: one wave per output block (b,k) ----
constexpr int KCHUNK = 16;                       // blocks per workgroup (4 waves x 4)
constexpr int NCHUNK = (NB + KCHUNK - 1) / KCHUNK;  // 28

__global__ __launch_bounds__(256) void hd_kernel(
    const float* __restrict__ X, const int* __restrict__ S,
    const float* __restrict__ PM, const float* __restrict__ C,
    const int* __restrict__ PARA, const float* __restrict__ IX,
    const float* __restrict__ HT, float* __restrict__ out) {
  __shared__ float sHT[(VOC + 1) * HD];
  for (int i = threadIdx.x; i < (VOC + 1) * HD / 4; i += 256)
    ((float4*)sHT)[i] = ((const float4*)HT)[i];
  __syncthreads();

  const int b    = blockIdx.x;
  const int wave = threadIdx.x >> 6;
  const int lane = threadIdx.x & 63;
  const float4* sp = (const float4*)sHT;   // row v at sp[v*64 + lane]

  for (int i = 0; i < KCHUNK / 4; ++i) {
    const int k = blockIdx.y * KCHUNK + wave * (KCHUNK / 4) + i;
    if (k >= NB) break;

    int mode, pos0, cnt;
    if (k < NB_PRE)               { mode = 0; pos0 = k * BSZ;                      cnt = min(BSZ, L_ - pos0); }
    else if (k < NB_PRE + MIDN)   { mode = 1; pos0 = L_ + (k - NB_PRE);            cnt = 1; }
    else                          { mode = 0; pos0 = (R_ + 1) + (k - NB_PRE - MIDN) * BSZ; cnt = min(BSZ, N_ - pos0); }

    float4 acc = make_float4(0.f, 0.f, 0.f, 0.f);
    float msum = 0.f, mmax = 0.f, xacc = 0.f, pmv = 0.f;

    for (int p = 0; p < cnt; ++p) {
      const size_t idx = (size_t)b * N_ + (pos0 + p);
      const float m   = PM[idx];
      const bool  sel = PARA[idx] > 0;
      const float w   = mode ? 1.f : m;

      if (sel) {
        const float* cp = C + idx * VOC;
#pragma unroll
        for (int v = 0; v < VOC; ++v) {
          const float a = w * cp[v];
          const float4 hv = sp[v * (HD / 4) + lane];
          acc.x = fmaf(a, hv.x, acc.x);
          acc.y = fmaf(a, hv.y, acc.y);
          acc.z = fmaf(a, hv.z, acc.z);
          acc.w = fmaf(a, hv.w, acc.w);
        }
        pmv = 1.f;
      } else {
        const int s = S[idx];
        const float4 hv = sp[s * (HD / 4) + lane];
        acc.x = fmaf(w, hv.x, acc.x);
        acc.y = fmaf(w, hv.y, acc.y);
        acc.z = fmaf(w, hv.z, acc.z);
        acc.w = fmaf(w, hv.w, acc.w);
      }
      msum += w;
      mmax = fmaxf(mmax, m);

      if (lane < 12) {
        xacc = fmaf(w, X[idx * 12 + lane], xacc);
      } else if (lane < 24) {
        const int cc = lane - 12;
        const float xv = sel ? IX[idx * 12 + cc] : X[idx * 12 + cc];
        xacc = fmaf(w, xv, xacc);
      }
    }

    // bias row (W_b) weighted by msum, then scale by 1/(msum+eps) for block mode
    {
      const float4 hb = sp[VOC * (HD / 4) + lane];
      acc.x = fmaf(msum, hb.x, acc.x);
      acc.y = fmaf(msum, hb.y, acc.y);
      acc.z = fmaf(msum, hb.z, acc.z);
      acc.w = fmaf(msum, hb.w, acc.w);
    }
    const float inv = mode ? 1.f : 1.f / (msum + EPS_);

    const size_t base = (size_t)b * NB + k;
    float4 o = make_float4(acc.x * inv, acc.y * inv, acc.z * inv, acc.w * inv);
    ((float4*)(out + OFF_BS))[base * (HD / 4) + lane] = o;

    if (lane < 12)        out[OFF_BX  + base * 12 + lane]        = xacc * inv;
    else if (lane < 24)   out[OFF_BIX + base * 12 + (lane - 12)] = xacc * inv;
    else if (lane == 24)  out[OFF_PM  + base] = mode ? pmv : 0.f;
    else if (lane == 25)  out[OFF_BM  + base] = mmax;
  }
}

extern "C" void kernel_launch(void* const* d_in, const int* in_sizes, int n_in,
                              void* d_out, int out_size, void* d_ws, size_t ws_size,
                              hipStream_t stream) {
  const float* X    = (const float*)d_in[0];
  const int*   S    = (const int*)  d_in[1];
  const float* PM   = (const float*)d_in[2];
  const float* C    = (const float*)d_in[3];
  const int*   PARA = (const int*)  d_in[4];
  const float* IX   = (const float*)d_in[5];
  const float* EMB  = (const float*)d_in[6];
  const float* WW   = (const float*)d_in[7];
  const float* WB   = (const float*)d_in[8];
  float* out = (float*)d_out;
  float* ht  = (float*)d_ws;   // 22*256 floats = 22528 B

  hipLaunchKernelGGL(ht_kernel, dim3(VOC + 1), dim3(HD), 0, stream, EMB, WW, WB, ht);
  hipLaunchKernelGGL(hd_kernel, dim3(B_, NCHUNK), dim3(256), 0, stream,
                     X, S, PM, C, PARA, IX, ht, out);
}

// Round 2
// 30.774 us; speedup vs baseline: 1.5244x; 1.5244x over previous
//
#include <hip/hip_runtime.h>
#include <cstddef>

// ---- problem constants (from setup_inputs: fixed for this benchmark) ----
constexpr int B_   = 64;
constexpr int N_   = 2048;
constexpr int VOC  = 21;
constexpr int EMBD = 128;
constexpr int HD   = 256;
constexpr int L_   = 900;    // T_min
constexpr int R_   = 1100;   // T_max
constexpr int BSZ  = 8;      // block_size

constexpr int NB_PRE = (L_ + BSZ - 1) / BSZ;               // 113
constexpr int MIDN   = R_ - L_ + 1;                        // 201
constexpr int NB_SUF = (N_ - (R_ + 1) + BSZ - 1) / BSZ;    // 119
constexpr int NB     = NB_PRE + MIDN + NB_SUF;             // 433

constexpr float EPS_ = 1e-8f;

// output layout: bS, bX, pm_blocks, b_init_X, bmask concatenated flat
constexpr size_t OFF_BS  = 0;
constexpr size_t OFF_BX  = (size_t)B_ * NB * HD;               // 7094272
constexpr size_t OFF_PM  = OFF_BX  + (size_t)B_ * NB * 12;     // 7426816
constexpr size_t OFF_BIX = OFF_PM  + (size_t)B_ * NB;          // 7454528
constexpr size_t OFF_BM  = OFF_BIX + (size_t)B_ * NB * 12;     // 7787072

// ---- kernel A: HT2[22][256] = [emb_table @ W_w ; W_b] ----
__global__ void ht_kernel(const float* __restrict__ emb,
                          const float* __restrict__ Ww,
                          const float* __restrict__ Wb,
                          float* __restrict__ ht) {
  const int v = blockIdx.x;
  const int h = threadIdx.x;
  if (v == VOC) { ht[(size_t)VOC * HD + h] = Wb[h]; return; }
  const float* e = emb + (size_t)v * EMBD;
  float a0 = 0.f, a1 = 0.f, a2 = 0.f, a3 = 0.f;
#pragma unroll
  for (int k = 0; k < EMBD; k += 4) {
    a0 = fmaf(e[k + 0], Ww[(size_t)(k + 0) * HD + h], a0);
    a1 = fmaf(e[k + 1], Ww[(size_t)(k + 1) * HD + h], a1);
    a2 = fmaf(e[k + 2], Ww[(size_t)(k + 2) * HD + h], a2);
    a3 = fmaf(e[k + 3], Ww[(size_t)(k + 3) * HD + h], a3);
  }
  ht[(size_t)v * HD + h] = (a0 + a1) + (a2 + a3);
}

// ---- kernel B: one WAVE per output block (b,k); no LDS, HT via L1 ----
__global__ __launch_bounds__(256) void hd_kernel(
    const float* __restrict__ X, const int* __restrict__ S,
    const float* __restrict__ PM, const float* __restrict__ C,
    const int* __restrict__ PARA, const float* __restrict__ IX,
    const float* __restrict__ HT, float* __restrict__ out) {
  const int wave = threadIdx.x >> 6;
  const int lane = threadIdx.x & 63;
  const int k = blockIdx.x * 4 + wave;
  if (k >= NB) return;
  const int b = blockIdx.y;
  const float4* hp = (const float4*)HT;   // row v at hp[v*64 + lane]

  int mode, pos0, cnt;
  if (k < NB_PRE)               { mode = 1; pos0 = k * BSZ;                      cnt = min(BSZ, L_ - pos0); }
  else if (k < NB_PRE + MIDN)   { mode = 0; pos0 = L_ + (k - NB_PRE);            cnt = 1; }
  else                          { mode = 1; pos0 = (R_ + 1) + (k - NB_PRE - MIDN) * BSZ; cnt = min(BSZ, N_ - pos0); }
  // mode: 1 = block-mean, 0 = mid passthrough

  float4 acc = make_float4(0.f, 0.f, 0.f, 0.f);
  float msum = 0.f, mmax = 0.f, xacc = 0.f, pmv = 0.f;

  if (!mode) {
    // -------- mid region: single position, w = 1 --------
    const size_t idx = (size_t)b * N_ + pos0;
    const float m = PM[idx];
    const bool sel = PARA[idx] > 0;
    if (sel) {
      const float* cp = C + idx * VOC;
#pragma unroll
      for (int v = 0; v < VOC; ++v) {
        const float a = cp[v];
        const float4 hv = hp[v * (HD / 4) + lane];
        acc.x = fmaf(a, hv.x, acc.x);
        acc.y = fmaf(a, hv.y, acc.y);
        acc.z = fmaf(a, hv.z, acc.z);
        acc.w = fmaf(a, hv.w, acc.w);
      }
      pmv = 1.f;
    } else {
      acc = hp[S[idx] * (HD / 4) + lane];
    }
    msum = 1.f; mmax = m;
    if (lane < 12) {
      xacc = X[idx * 12 + lane];
    } else if (lane < 24) {
      const int cc = lane - 12;
      xacc = sel ? IX[idx * 12 + cc] : X[idx * 12 + cc];
    }
  } else {
    // -------- block-mean region --------
    const size_t idx0 = (size_t)b * N_ + pos0;
    bool slow = true;
    if (cnt == BSZ) {
      // bulk uniform loads, all independent
      float m[BSZ]; int pr[BSZ]; int sv[BSZ];
#pragma unroll
      for (int p = 0; p < BSZ; ++p) {
        m[p]  = PM[idx0 + p];
        pr[p] = PARA[idx0 + p];
        sv[p] = S[idx0 + p];
      }
      int anysel = 0;
#pragma unroll
      for (int p = 0; p < BSZ; ++p) anysel |= pr[p];
      if (anysel <= 0) {
        slow = false;
        float xw[BSZ];
        if (lane < 24) {
          const int cc = (lane < 12) ? lane : (lane - 12);
#pragma unroll
          for (int p = 0; p < BSZ; ++p) xw[p] = X[(idx0 + p) * 12 + cc];
        }
#pragma unroll
        for (int p = 0; p < BSZ; ++p) {
          const float w = m[p];
          const float4 hv = hp[sv[p] * (HD / 4) + lane];
          acc.x = fmaf(w, hv.x, acc.x);
          acc.y = fmaf(w, hv.y, acc.y);
          acc.z = fmaf(w, hv.z, acc.z);
          acc.w = fmaf(w, hv.w, acc.w);
          msum += w;
          mmax = fmaxf(mmax, w);
          if (lane < 24) xacc = fmaf(w, xw[p], xacc);
        }
      }
    }
    if (slow) {
      // general fallback: ragged tail blocks, or paratope inside a block
      for (int p = 0; p < cnt; ++p) {
        const size_t idx = idx0 + p;
        const float m = PM[idx];
        const bool sel = PARA[idx] > 0;
        const float w = m;
        if (sel) {
          const float* cp = C + idx * VOC;
#pragma unroll
          for (int v = 0; v < VOC; ++v) {
            const float a = w * cp[v];
            const float4 hv = hp[v * (HD / 4) + lane];
            acc.x = fmaf(a, hv.x, acc.x);
            acc.y = fmaf(a, hv.y, acc.y);
            acc.z = fmaf(a, hv.z, acc.z);
            acc.w = fmaf(a, hv.w, acc.w);
          }
        } else {
          const float4 hv = hp[S[idx] * (HD / 4) + lane];
          acc.x = fmaf(w, hv.x, acc.x);
          acc.y = fmaf(w, hv.y, acc.y);
          acc.z = fmaf(w, hv.z, acc.z);
          acc.w = fmaf(w, hv.w, acc.w);
        }
        msum += w;
        mmax = fmaxf(mmax, m);
        if (lane < 12) {
          xacc = fmaf(w, X[idx * 12 + lane], xacc);
        } else if (lane < 24) {
          const int cc = lane - 12;
          const float xv = sel ? IX[idx * 12 + cc] : X[idx * 12 + cc];
          xacc = fmaf(w, xv, xacc);
        }
      }
    }
  }

  // bias row (W_b) weighted by msum, then 1/(msum+eps) in block mode
  {
    const float4 hb = hp[VOC * (HD / 4) + lane];
    acc.x = fmaf(msum, hb.x, acc.x);
    acc.y = fmaf(msum, hb.y, acc.y);
    acc.z = fmaf(msum, hb.z, acc.z);
    acc.w = fmaf(msum, hb.w, acc.w);
  }
  const float inv = mode ? 1.f / (msum + EPS_) : 1.f;

  const size_t base = (size_t)b * NB + k;
  float4 o = make_float4(acc.x * inv, acc.y * inv, acc.z * inv, acc.w * inv);
  ((float4*)(out + OFF_BS))[base * (HD / 4) + lane] = o;

  if (lane < 12)        out[OFF_BX  + base * 12 + lane]        = xacc * inv;
  else if (lane < 24)   out[OFF_BIX + base * 12 + (lane - 12)] = xacc * inv;
  else if (lane == 24)  out[OFF_PM  + base] = mode ? 0.f : pmv;
  else if (lane == 25)  out[OFF_BM  + base] = mmax;
}

extern "C" void kernel_launch(void* const* d_in, const int* in_sizes, int n_in,
                              void* d_out, int out_size, void* d_ws, size_t ws_size,
                              hipStream_t stream) {
  const float* X    = (const float*)d_in[0];
  const int*   S    = (const int*)  d_in[1];
  const float* PM   = (const float*)d_in[2];
  const float* C    = (const float*)d_in[3];
  const int*   PARA = (const int*)  d_in[4];
  const float* IX   = (const float*)d_in[5];
  const float* EMB  = (const float*)d_in[6];
  const float* WW   = (const float*)d_in[7];
  const float* WB   = (const float*)d_in[8];
  float* out = (float*)d_out;
  float* ht  = (float*)d_ws;   // 22*256 floats = 22528 B

  hipLaunchKernelGGL(ht_kernel, dim3(VOC + 1), dim3(HD), 0, stream, EMB, WW, WB, ht);
  hipLaunchKernelGGL(hd_kernel, dim3((NB + 3) / 4, B_), dim3(256), 0, stream,
                     X, S, PM, C, PARA, IX, ht, out);
}

// Round 3
// 27.529 us; speedup vs baseline: 1.7041x; 1.1179x over previous
//
#include <hip/hip_runtime.h>
#include <cstddef>

typedef float f32x4 __attribute__((ext_vector_type(4)));

// ---- problem constants (from setup_inputs: fixed for this benchmark) ----
constexpr int B_   = 64;
constexpr int N_   = 2048;
constexpr int VOC  = 21;
constexpr int EMBD = 128;
constexpr int HD   = 256;
constexpr int L_   = 900;    // T_min
constexpr int R_   = 1100;   // T_max
constexpr int BSZ  = 8;      // block_size

constexpr int NB_PRE = (L_ + BSZ - 1) / BSZ;               // 113
constexpr int MIDN   = R_ - L_ + 1;                        // 201
constexpr int NB_SUF = (N_ - (R_ + 1) + BSZ - 1) / BSZ;    // 119
constexpr int NB     = NB_PRE + MIDN + NB_SUF;             // 433

constexpr float EPS_ = 1e-8f;

// output layout: bS, bX, pm_blocks, b_init_X, bmask concatenated flat
constexpr size_t OFF_BS  = 0;
constexpr size_t OFF_BX  = (size_t)B_ * NB * HD;               // 7094272
constexpr size_t OFF_PM  = OFF_BX  + (size_t)B_ * NB * 12;     // 7426816
constexpr size_t OFF_BIX = OFF_PM  + (size_t)B_ * NB;          // 7454528
constexpr size_t OFF_BM  = OFF_BIX + (size_t)B_ * NB * 12;     // 7787072

// ---- kernel A: HTb[21][256] = emb_table @ W_w + W_b (bias folded in) ----
__global__ void ht_kernel(const float* __restrict__ emb,
                          const float* __restrict__ Ww,
                          const float* __restrict__ Wb,
                          float* __restrict__ ht) {
  const int v = blockIdx.x;
  const int h = threadIdx.x;
  const float* e = emb + (size_t)v * EMBD;
  float a0 = 0.f, a1 = 0.f, a2 = 0.f, a3 = 0.f;
#pragma unroll
  for (int k = 0; k < EMBD; k += 4) {
    a0 = fmaf(e[k + 0], Ww[(size_t)(k + 0) * HD + h], a0);
    a1 = fmaf(e[k + 1], Ww[(size_t)(k + 1) * HD + h], a1);
    a2 = fmaf(e[k + 2], Ww[(size_t)(k + 2) * HD + h], a2);
    a3 = fmaf(e[k + 3], Ww[(size_t)(k + 3) * HD + h], a3);
  }
  ht[(size_t)v * HD + h] = (a0 + a1) + (a2 + a3) + Wb[h];
}

// ---- kernel B: one WAVE per output block (b,k); no LDS, HTb via L1 ----
__global__ __launch_bounds__(256) void hd_kernel(
    const float* __restrict__ X, const int* __restrict__ S,
    const float* __restrict__ PM, const float* __restrict__ C,
    const int* __restrict__ PARA, const float* __restrict__ IX,
    const float* __restrict__ HT, float* __restrict__ out) {
  const int wave = threadIdx.x >> 6;
  const int lane = threadIdx.x & 63;
  const int k = blockIdx.x * 4 + wave;
  if (k >= NB) return;
  const int b = blockIdx.y;
  const f32x4* hp = (const f32x4*)HT;   // row v at hp[v*64 + lane]
  const size_t base = (size_t)b * NB + k;
  f32x4* bs_out = (f32x4*)(out + OFF_BS);

  if (k >= NB_PRE && k < NB_PRE + MIDN) {
    // -------- mid region: single position passthrough --------
    const int pos = L_ + (k - NB_PRE);
    const size_t idx = (size_t)b * N_ + pos;
    const float m = PM[idx];
    const bool sel = PARA[idx] > 0;
    f32x4 acc;
    if (sel) {
      const float* cp = C + idx * VOC;
      acc = cp[0] * hp[lane];
#pragma unroll
      for (int v = 1; v < VOC; ++v) {
        const float a = cp[v];
        acc += a * hp[v * (HD / 4) + lane];
      }
    } else {
      acc = hp[S[idx] * (HD / 4) + lane];
    }
    __builtin_nontemporal_store(acc, &bs_out[base * (HD / 4) + lane]);
    if (lane < 12) {
      __builtin_nontemporal_store(X[idx * 12 + lane], &out[OFF_BX + base * 12 + lane]);
    } else if (lane < 24) {
      const int cc = lane - 12;
      const float xv = sel ? IX[idx * 12 + cc] : X[idx * 12 + cc];
      __builtin_nontemporal_store(xv, &out[OFF_BIX + base * 12 + cc]);
    } else if (lane == 24) {
      __builtin_nontemporal_store(sel ? 1.f : 0.f, &out[OFF_PM + base]);
    } else if (lane == 25) {
      __builtin_nontemporal_store(m, &out[OFF_BM + base]);
    }
    return;
  }

  // -------- block-mean region --------
  int pos0, cnt;
  if (k < NB_PRE) { pos0 = k * BSZ;                              cnt = min(BSZ, L_ - pos0); }
  else            { pos0 = (R_ + 1) + (k - NB_PRE - MIDN) * BSZ; cnt = min(BSZ, N_ - pos0); }
  const size_t idx0 = (size_t)b * N_ + pos0;

  f32x4 acc = {0.f, 0.f, 0.f, 0.f};
  float msum = 0.f, mmax = 0.f;
  bool slow = true;

  if (cnt == BSZ) {
    float mv[BSZ]; int pr[BSZ]; int sv[BSZ];
#pragma unroll
    for (int p = 0; p < BSZ; ++p) {
      mv[p] = PM[idx0 + p];
      pr[p] = PARA[idx0 + p];
      sv[p] = S[idx0 + p];
    }
    int anysel = 0;
#pragma unroll
    for (int p = 0; p < BSZ; ++p) anysel |= pr[p];
    if (anysel <= 0) {
      slow = false;
#pragma unroll
      for (int p = 0; p < BSZ; ++p) {
        const float w = mv[p];
        acc += w * hp[sv[p] * (HD / 4) + lane];
        msum += w;
        mmax = fmaxf(mmax, w);
      }
      // X weighted sum: 4 lane-groups of 12, 2 positions each, shuffle-reduce
      const int cc = lane % 12;
      const int g  = lane / 12;
      float xa = 0.f;
      if (lane < 48) {
        xa = mv[2 * g] * X[(idx0 + 2 * g) * 12 + cc]
           + mv[2 * g + 1] * X[(idx0 + 2 * g + 1) * 12 + cc];
      }
      xa += __shfl(xa, lane + 24, 64);   // lanes 0-23 pick up groups 2,3
      xa += __shfl(xa, lane + 12, 64);   // lanes 0-11 pick up (g1+g3)

      const float inv = 1.f / (msum + EPS_);
      f32x4 o = acc * inv;
      __builtin_nontemporal_store(o, &bs_out[base * (HD / 4) + lane]);
      if (lane < 12) {
        const float xv = xa * inv;
        __builtin_nontemporal_store(xv, &out[OFF_BX  + base * 12 + lane]);
        __builtin_nontemporal_store(xv, &out[OFF_BIX + base * 12 + lane]);
      } else if (lane == 24) {
        __builtin_nontemporal_store(0.f, &out[OFF_PM + base]);
      } else if (lane == 25) {
        __builtin_nontemporal_store(mmax, &out[OFF_BM + base]);
      }
      return;
    }
  }

  if (slow) {
    // general fallback: ragged tail blocks, or paratope inside a block
    float xacc = 0.f;
    for (int p = 0; p < cnt; ++p) {
      const size_t idx = idx0 + p;
      const float m = PM[idx];
      const bool sel = PARA[idx] > 0;
      const float w = m;
      if (sel) {
        const float* cp = C + idx * VOC;
#pragma unroll
        for (int v = 0; v < VOC; ++v) {
          acc += (w * cp[v]) * hp[v * (HD / 4) + lane];
        }
      } else {
        acc += w * hp[S[idx] * (HD / 4) + lane];
      }
      msum += w;
      mmax = fmaxf(mmax, m);
      if (lane < 12) {
        xacc = fmaf(w, X[idx * 12 + lane], xacc);
      } else if (lane < 24) {
        const int cc = lane - 12;
        const float xv = sel ? IX[idx * 12 + cc] : X[idx * 12 + cc];
        xacc = fmaf(w, xv, xacc);
      }
    }
    const float inv = 1.f / (msum + EPS_);
    f32x4 o = acc * inv;
    __builtin_nontemporal_store(o, &bs_out[base * (HD / 4) + lane]);
    if (lane < 12) {
      __builtin_nontemporal_store(xacc * inv, &out[OFF_BX + base * 12 + lane]);
    } else if (lane < 24) {
      __builtin_nontemporal_store(xacc * inv, &out[OFF_BIX + base * 12 + (lane - 12)]);
    } else if (lane == 24) {
      __builtin_nontemporal_store(0.f, &out[OFF_PM + base]);
    } else if (lane == 25) {
      __builtin_nontemporal_store(mmax, &out[OFF_BM + base]);
    }
  }
}

extern "C" void kernel_launch(void* const* d_in, const int* in_sizes, int n_in,
                              void* d_out, int out_size, void* d_ws, size_t ws_size,
                              hipStream_t stream) {
  const float* X    = (const float*)d_in[0];
  const int*   S    = (const int*)  d_in[1];
  const float* PM   = (const float*)d_in[2];
  const float* C    = (const float*)d_in[3];
  const int*   PARA = (const int*)  d_in[4];
  const float* IX   = (const float*)d_in[5];
  const float* EMB  = (const float*)d_in[6];
  const float* WW   = (const float*)d_in[7];
  const float* WB   = (const float*)d_in[8];
  float* out = (float*)d_out;
  float* ht  = (float*)d_ws;   // 21*256 floats = 21504 B

  hipLaunchKernelGGL(ht_kernel, dim3(VOC), dim3(HD), 0, stream, EMB, WW, WB, ht);
  hipLaunchKernelGGL(hd_kernel, dim3((NB + 3) / 4, B_), dim3(256), 0, stream,
                     X, S, PM, C, PARA, IX, ht, out);
}

// Round 4
// 27.517 us; speedup vs baseline: 1.7048x; 1.0004x over previous
//
#include <hip/hip_runtime.h>
#include <cstddef>

typedef float f32x4 __attribute__((ext_vector_type(4)));
typedef int   i32x4 __attribute__((ext_vector_type(4)));

// ---- problem constants (from setup_inputs: fixed for this benchmark) ----
constexpr int B_   = 64;
constexpr int N_   = 2048;
constexpr int VOC  = 21;
constexpr int EMBD = 128;
constexpr int HD   = 256;
constexpr int L_   = 900;    // T_min
constexpr int R_   = 1100;   // T_max
constexpr int BSZ  = 8;      // block_size

constexpr int NB_PRE = (L_ + BSZ - 1) / BSZ;               // 113
constexpr int MIDN   = R_ - L_ + 1;                        // 201
constexpr int NB_SUF = (N_ - (R_ + 1) + BSZ - 1) / BSZ;    // 119
constexpr int NB     = NB_PRE + MIDN + NB_SUF;             // 433

constexpr float EPS_ = 1e-8f;

// output layout: bS, bX, pm_blocks, b_init_X, bmask concatenated flat
constexpr size_t OFF_BS  = 0;
constexpr size_t OFF_BX  = (size_t)B_ * NB * HD;               // 7094272
constexpr size_t OFF_PM  = OFF_BX  + (size_t)B_ * NB * 12;     // 7426816
constexpr size_t OFF_BIX = OFF_PM  + (size_t)B_ * NB;          // 7454528
constexpr size_t OFF_BM  = OFF_BIX + (size_t)B_ * NB * 12;     // 7787072

// ---- kernel A: HTb[21][256] = emb_table @ W_w + W_b (bias folded in) ----
__global__ __launch_bounds__(256) void ht_kernel(
    const float* __restrict__ emb, const float* __restrict__ Ww,
    const float* __restrict__ Wb, float* __restrict__ ht) {
  const int v = blockIdx.x;
  const int h = threadIdx.x;
  const f32x4* e4 = (const f32x4*)(emb + (size_t)v * EMBD);
  float a0 = 0.f, a1 = 0.f, a2 = 0.f, a3 = 0.f;
#pragma unroll
  for (int k = 0; k < EMBD / 4; ++k) {
    const f32x4 e = e4[k];
    a0 = fmaf(e.x, Ww[(size_t)(4 * k + 0) * HD + h], a0);
    a1 = fmaf(e.y, Ww[(size_t)(4 * k + 1) * HD + h], a1);
    a2 = fmaf(e.z, Ww[(size_t)(4 * k + 2) * HD + h], a2);
    a3 = fmaf(e.w, Ww[(size_t)(4 * k + 3) * HD + h], a3);
  }
  ht[(size_t)v * HD + h] = (a0 + a1) + (a2 + a3) + Wb[h];
}

// ---- kernel B: one WAVE per output block (b,k); no LDS, HTb via L1 ----
__global__ __launch_bounds__(256) void hd_kernel(
    const float* __restrict__ X, const int* __restrict__ S,
    const float* __restrict__ PM, const float* __restrict__ C,
    const int* __restrict__ PARA, const float* __restrict__ IX,
    const float* __restrict__ HT, float* __restrict__ out) {
  const int wave = threadIdx.x >> 6;
  const int lane = threadIdx.x & 63;
  const int k = blockIdx.x * 4 + wave;
  if (k >= NB) return;
  const int b = blockIdx.y;
  const f32x4* hp = (const f32x4*)HT;   // row v at hp[v*64 + lane]
  const size_t base = (size_t)b * NB + k;
  f32x4* bs_out = (f32x4*)(out + OFF_BS);

  if (k >= NB_PRE && k < NB_PRE + MIDN) {
    // -------- mid region: single position passthrough (all loads hoisted) --------
    const int pos = L_ + (k - NB_PRE);
    const size_t idx = (size_t)b * N_ + pos;
    const float m  = PM[idx];
    const int   pr = PARA[idx];
    const int   s  = S[idx];
    float xA = 0.f, xB = 0.f;
    if (lane < 12) {
      xA = X[idx * 12 + lane];
    } else if (lane < 24) {
      xA = X[idx * 12 + (lane - 12)];
      xB = IX[idx * 12 + (lane - 12)];
    }
    const float cv = (lane < VOC) ? C[idx * VOC + lane] : 0.f;
    const bool sel = pr > 0;   // wave-uniform
    f32x4 acc;
    if (sel) {
      acc = __shfl(cv, 0, 64) * hp[lane];
#pragma unroll
      for (int v = 1; v < VOC; ++v)
        acc += __shfl(cv, v, 64) * hp[v * (HD / 4) + lane];
    } else {
      acc = hp[s * (HD / 4) + lane];
    }
    __builtin_nontemporal_store(acc, &bs_out[base * (HD / 4) + lane]);
    if (lane < 12) {
      __builtin_nontemporal_store(xA, &out[OFF_BX + base * 12 + lane]);
    } else if (lane < 24) {
      __builtin_nontemporal_store(sel ? xB : xA, &out[OFF_BIX + base * 12 + (lane - 12)]);
    } else if (lane == 24) {
      __builtin_nontemporal_store(sel ? 1.f : 0.f, &out[OFF_PM + base]);
    } else if (lane == 25) {
      __builtin_nontemporal_store(m, &out[OFF_BM + base]);
    }
    return;
  }

  // -------- block-mean region --------
  int pos0, cnt;
  if (k < NB_PRE) { pos0 = k * BSZ;                              cnt = min(BSZ, L_ - pos0); }
  else            { pos0 = (R_ + 1) + (k - NB_PRE - MIDN) * BSZ; cnt = min(BSZ, N_ - pos0); }
  const size_t idx0 = (size_t)b * N_ + pos0;

  if (cnt == BSZ) {
    // vectorized uniform index loads
    float mv[BSZ]; int pr[BSZ]; int sv[BSZ];
    if (k < NB_PRE) {
      // idx0 is 32B-aligned (pos0 = 8k, b*N aligned)
      const f32x4 ma = *(const f32x4*)(PM + idx0);
      const f32x4 mb = *(const f32x4*)(PM + idx0 + 4);
      const i32x4 pa = *(const i32x4*)(PARA + idx0);
      const i32x4 pb = *(const i32x4*)(PARA + idx0 + 4);
      const i32x4 sa = *(const i32x4*)(S + idx0);
      const i32x4 sb = *(const i32x4*)(S + idx0 + 4);
      mv[0]=ma.x; mv[1]=ma.y; mv[2]=ma.z; mv[3]=ma.w; mv[4]=mb.x; mv[5]=mb.y; mv[6]=mb.z; mv[7]=mb.w;
      pr[0]=pa.x; pr[1]=pa.y; pr[2]=pa.z; pr[3]=pa.w; pr[4]=pb.x; pr[5]=pb.y; pr[6]=pb.z; pr[7]=pb.w;
      sv[0]=sa.x; sv[1]=sa.y; sv[2]=sa.z; sv[3]=sa.w; sv[4]=sb.x; sv[5]=sb.y; sv[6]=sb.z; sv[7]=sb.w;
    } else {
      // suffix: idx0 % 4 == 1 -> shifted aligned window [idx0-1, idx0+7) + tail
      const f32x4 ma = *(const f32x4*)(PM + idx0 - 1);
      const f32x4 mb = *(const f32x4*)(PM + idx0 + 3);
      const float mt = PM[idx0 + 7];
      const i32x4 pa = *(const i32x4*)(PARA + idx0 - 1);
      const i32x4 pb = *(const i32x4*)(PARA + idx0 + 3);
      const int   pt = PARA[idx0 + 7];
      const i32x4 sa = *(const i32x4*)(S + idx0 - 1);
      const i32x4 sb = *(const i32x4*)(S + idx0 + 3);
      const int   st = S[idx0 + 7];
      mv[0]=ma.y; mv[1]=ma.z; mv[2]=ma.w; mv[3]=mb.x; mv[4]=mb.y; mv[5]=mb.z; mv[6]=mb.w; mv[7]=mt;
      pr[0]=pa.y; pr[1]=pa.z; pr[2]=pa.w; pr[3]=pb.x; pr[4]=pb.y; pr[5]=pb.z; pr[6]=pb.w; pr[7]=pt;
      sv[0]=sa.y; sv[1]=sa.z; sv[2]=sa.w; sv[3]=sb.x; sv[4]=sb.y; sv[5]=sb.z; sv[6]=sb.w; sv[7]=st;
    }
    int anysel = 0;
#pragma unroll
    for (int p = 0; p < BSZ; ++p) anysel |= pr[p];
    if (anysel <= 0) {
      // X weighted sum: 4 lane-groups of 12, 2 positions each, shuffle-reduce
      const int cc = lane % 12;
      const int g  = lane / 12;
      float x0 = 0.f, x1 = 0.f;
      if (lane < 48) {
        x0 = X[(idx0 + 2 * g) * 12 + cc];
        x1 = X[(idx0 + 2 * g + 1) * 12 + cc];
      }
      f32x4 acc = {0.f, 0.f, 0.f, 0.f};
      float msum = 0.f, mmax = 0.f;
#pragma unroll
      for (int p = 0; p < BSZ; ++p) {
        const float w = mv[p];
        acc += w * hp[sv[p] * (HD / 4) + lane];
        msum += w;
        mmax = fmaxf(mmax, w);
      }
      float xa = 0.f;
      if (lane < 48) xa = mv[2 * g] * x0 + mv[2 * g + 1] * x1;
      xa += __shfl(xa, lane + 24, 64);
      xa += __shfl(xa, lane + 12, 64);

      const float inv = 1.f / (msum + EPS_);
      const f32x4 o = acc * inv;
      __builtin_nontemporal_store(o, &bs_out[base * (HD / 4) + lane]);
      if (lane < 12) {
        const float xv = xa * inv;
        __builtin_nontemporal_store(xv, &out[OFF_BX  + base * 12 + lane]);
        __builtin_nontemporal_store(xv, &out[OFF_BIX + base * 12 + lane]);
      } else if (lane == 24) {
        __builtin_nontemporal_store(0.f, &out[OFF_PM + base]);
      } else if (lane == 25) {
        __builtin_nontemporal_store(mmax, &out[OFF_BM + base]);
      }
      return;
    }
  }

  // general fallback: ragged tail blocks, or paratope inside a block
  {
    f32x4 acc = {0.f, 0.f, 0.f, 0.f};
    float msum = 0.f, mmax = 0.f, xacc = 0.f;
    for (int p = 0; p < cnt; ++p) {
      const size_t idx = idx0 + p;
      const float m = PM[idx];
      const bool sel = PARA[idx] > 0;
      const float w = m;
      if (sel) {
        const float* cp = C + idx * VOC;
#pragma unroll
        for (int v = 0; v < VOC; ++v) {
          acc += (w * cp[v]) * hp[v * (HD / 4) + lane];
        }
      } else {
        acc += w * hp[S[idx] * (HD / 4) + lane];
      }
      msum += w;
      mmax = fmaxf(mmax, m);
      if (lane < 12) {
        xacc = fmaf(w, X[idx * 12 + lane], xacc);
      } else if (lane < 24) {
        const int cc = lane - 12;
        const float xv = sel ? IX[idx * 12 + cc] : X[idx * 12 + cc];
        xacc = fmaf(w, xv, xacc);
      }
    }
    const float inv = 1.f / (msum + EPS_);
    const f32x4 o = acc * inv;
    __builtin_nontemporal_store(o, &bs_out[base * (HD / 4) + lane]);
    if (lane < 12) {
      __builtin_nontemporal_store(xacc * inv, &out[OFF_BX + base * 12 + lane]);
    } else if (lane < 24) {
      __builtin_nontemporal_store(xacc * inv, &out[OFF_BIX + base * 12 + (lane - 12)]);
    } else if (lane == 24) {
      __builtin_nontemporal_store(0.f, &out[OFF_PM + base]);
    } else if (lane == 25) {
      __builtin_nontemporal_store(mmax, &out[OFF_BM + base]);
    }
  }
}

extern "C" void kernel_launch(void* const* d_in, const int* in_sizes, int n_in,
                              void* d_out, int out_size, void* d_ws, size_t ws_size,
                              hipStream_t stream) {
  const float* X    = (const float*)d_in[0];
  const int*   S    = (const int*)  d_in[1];
  const float* PM   = (const float*)d_in[2];
  const float* C    = (const float*)d_in[3];
  const int*   PARA = (const int*)  d_in[4];
  const float* IX   = (const float*)d_in[5];
  const float* EMB  = (const float*)d_in[6];
  const float* WW   = (const float*)d_in[7];
  const float* WB   = (const float*)d_in[8];
  float* out = (float*)d_out;
  float* ht  = (float*)d_ws;   // 21*256 floats = 21504 B

  hipLaunchKernelGGL(ht_kernel, dim3(VOC), dim3(HD), 0, stream, EMB, WW, WB, ht);
  hipLaunchKernelGGL(hd_kernel, dim3((NB + 3) / 4, B_), dim3(256), 0, stream,
                     X, S, PM, C, PARA, IX, ht, out);
}